// Round 7
// baseline (137.356 us; speedup 1.0000x reference)
//
#include <hip/hip_runtime.h>
#include <hip/hip_bf16.h>

#define B_ 4
#define T_ 256
#define S_ 256
#define D_ 512
#define TB 2   // t's per attention block

typedef __bf16 bf16x8 __attribute__((ext_vector_type(8)));
typedef float  floatx4 __attribute__((ext_vector_type(4)));

#define C2F 2.885390081777926f  // 2*log2(e)

static __device__ __forceinline__ unsigned short f2bf(float x) {
    __hip_bfloat16 h = __float2bfloat16(x);
    return *reinterpret_cast<unsigned short*>(&h);
}
static __device__ __forceinline__ float asf(unsigned int u) {
    float f; __builtin_memcpy(&f, &u, 4); return f;
}

// ---------------------------------------------------------------------------
// prep: z=3 -> fp32->bf16 convert of output & context (linear, float4).
//       z=0,1,2 -> transpose+convert Wq, Wc, Wout into n-major bf16 WT[n][k].
// ---------------------------------------------------------------------------
__global__ __launch_bounds__(256) void prep(
    const float* __restrict__ output, const float* __restrict__ context,
    const float* __restrict__ Wq, const float* __restrict__ Wc,
    const float* __restrict__ Wout,
    unsigned short* __restrict__ out_b, unsigned short* __restrict__ ctx_b,
    unsigned short* __restrict__ WqT, unsigned short* __restrict__ WcT,
    unsigned short* __restrict__ WoutT)
{
    const int tid = threadIdx.x;
    const int z = blockIdx.z;

    if (z == 3) {
        size_t i = ((size_t)(blockIdx.y * gridDim.x + blockIdx.x) * 256 + tid) * 4;
        #pragma unroll
        for (int rep = 0; rep < 2; ++rep) {
            const float* src = rep ? context : output;
            unsigned short* dst = rep ? ctx_b : out_b;
            float4 v = *(const float4*)(src + i);
            ushort4 p;
            p.x = f2bf(v.x); p.y = f2bf(v.y); p.z = f2bf(v.z); p.w = f2bf(v.w);
            *(ushort4*)(dst + i) = p;
        }
        return;
    }

    const float* W; unsigned short* WT; int K;
    if      (z == 0) { W = Wq;   WT = WqT;   K = 512;  }
    else if (z == 1) { W = Wc;   WT = WcT;   K = 512;  }
    else             { W = Wout; WT = WoutT; K = 1024; }

    const int n0 = blockIdx.x * 32;
    const int k0 = blockIdx.y * 32;
    if (k0 >= K) return;

    __shared__ float tile[32][33];
    const int c = tid & 31, r = tid >> 5;
    #pragma unroll
    for (int i = 0; i < 4; ++i)
        tile[r + 8 * i][c] = W[(size_t)(k0 + r + 8 * i) * D_ + n0 + c];
    __syncthreads();
    #pragma unroll
    for (int i = 0; i < 4; ++i)
        WT[(size_t)(n0 + r + 8 * i) * K + k0 + c] = f2bf(tile[c][r + 8 * i]);
}

// ---------------------------------------------------------------------------
// MFMA bf16 GEMM, 16m x 32n per wave (3 loads -> 2 MFMAs), 64m x 32n per
// block (4 waves stacked in m). 4096 waves total across z=4 -> 16 waves/CU.
// Barrier-free, fragments straight from L2. A: M x As row-major bf16.
// BT: n-major bf16, row stride Bs, k offset koff. K=512 for all variants.
// Epilogue modes:
//   1: fp32 C2F*(acc + aux[col])          (wqs)
//   3: bf16 C2F*acc -> [b][d>>3][s][d&7]  (uhb; rows are (b,s), col=d)
//   4: fp32 acc + aux[col]                (OB = output@Wout_bot + bout)
//   5: bf16 acc, natural [row][col]       (CW = context@Wout_top, (b,s) x d)
// ---------------------------------------------------------------------------
struct GArgs {
    const unsigned short* A;
    const unsigned short* BT;
    const float* aux;
    void* C;
    int As, Bs, koff, mode;
};

template<int K>
__global__ __launch_bounds__(256) void gemm2(GArgs g0, GArgs g1, GArgs g2, GArgs g3)
{
    const int z = blockIdx.z;
    GArgs g = (z == 0) ? g0 : (z == 1) ? g1 : (z == 2) ? g2 : g3;

    const int tid  = threadIdx.x;
    const int wave = tid >> 6, lane = tid & 63;
    const int l15  = lane & 15, quad = lane >> 4;
    const int m0 = blockIdx.y * 64 + wave * 16;
    const int n0 = blockIdx.x * 32;

    const unsigned short* Ap  = g.A + (size_t)(m0 + l15) * g.As + quad * 8;
    const unsigned short* Bp0 = g.BT + (size_t)(n0 + l15) * g.Bs + g.koff + quad * 8;
    const unsigned short* Bp1 = Bp0 + (size_t)16 * g.Bs;

    floatx4 acc[2];
    acc[0] = (floatx4){0.f, 0.f, 0.f, 0.f};
    acc[1] = (floatx4){0.f, 0.f, 0.f, 0.f};

    #pragma unroll 4
    for (int k = 0; k < K; k += 32) {
        bf16x8 a  = *(const bf16x8*)(Ap + k);
        bf16x8 b0 = *(const bf16x8*)(Bp0 + k);
        bf16x8 b1 = *(const bf16x8*)(Bp1 + k);
        acc[0] = __builtin_amdgcn_mfma_f32_16x16x32_bf16(a, b0, acc[0], 0, 0, 0);
        acc[1] = __builtin_amdgcn_mfma_f32_16x16x32_bf16(a, b1, acc[1], 0, 0, 0);
    }

    #pragma unroll
    for (int ni = 0; ni < 2; ++ni) {
        const int col = n0 + ni * 16 + l15;
        const int rbase = m0 + quad * 4;
        if (g.mode == 3) {
            unsigned short* Cb = (unsigned short*)g.C;
            #pragma unroll
            for (int r = 0; r < 4; ++r) {
                int row = rbase + r, bb = row >> 8, ss = row & 255;
                Cb[((size_t)(bb * 64 + (col >> 3)) * 256 + ss) * 8 + (col & 7)]
                    = f2bf(C2F * acc[ni][r]);
            }
        } else if (g.mode == 5) {
            unsigned short* Cb = (unsigned short*)g.C;
            #pragma unroll
            for (int r = 0; r < 4; ++r) {
                int row = rbase + r;
                Cb[(size_t)row * 512 + col] = f2bf(acc[ni][r]);
            }
        } else {
            float* Cf = (float*)g.C;
            float bv = g.aux ? g.aux[col] : 0.0f;
            #pragma unroll
            for (int r = 0; r < 4; ++r) {
                int row = rbase + r;
                float val = acc[ni][r] + bv;
                if (g.mode == 1) val *= C2F;
                Cf[(size_t)row * 512 + col] = val;
            }
        }
    }
}

// ---------------------------------------------------------------------------
// Fused score + masked softmax + final projection.
// 512 threads; block = TB=2 t's of one b; thread (s=tid&255, h=tid>>8) owns
// d-half [256h, 256h+256) in the score phase.
// wqs = C2*(output@Wq+bq) fp32 (LDS-staged, broadcast reads);
// uhb = bf16 C2*(context@Wc) in [b][d/8][s][8] -> 16B coalesced loads.
// tanh(x) = 1-2/(exp2(x')+1) with x' pre-scaled; A = sum_d v*r.
// Softmax shift-invariance: p = exp2(C2F*(Amin - A))  (Vsum cancels).
// Final: out[b,t,:] = attn_rows @ CW[b] + OB rows  (CW bf16 [b][s][d],
// coalesced across d-lanes; s split over thread halves, LDS-combined).
// ---------------------------------------------------------------------------
__global__ __launch_bounds__(512) void attn_fused(
    const float* __restrict__ wqs,            // (B,T,D) pre-scaled fp32
    const unsigned short* __restrict__ uhb,   // (B,D/8,S,8) pre-scaled bf16
    const unsigned short* __restrict__ CWb,   // (B,S,D) bf16
    const float* __restrict__ OB,             // (B,T,D) fp32
    const int*   __restrict__ mask,           // (B,S)
    const float* __restrict__ v,              // (D)
    float* __restrict__ attn_out,             // (B,T,S) fp32
    float* __restrict__ out)                  // (B,T,D) fp32
{
    const int bg  = blockIdx.x;
    const int b   = bg / (T_ / TB);
    const int t0  = (bg % (T_ / TB)) * TB;
    const int tid = threadIdx.x;
    const int s   = tid & 255;
    const int h   = tid >> 8;

    __shared__ float  w_s[TB][D_];       // 4 KB
    __shared__ float  v_s[D_];           // 2 KB
    __shared__ float2 part[2][256];      // 4 KB
    __shared__ float2 red[256];          // 2 KB
    __shared__ float  a_s[TB][256];      // 2 KB
    __shared__ float  mixp[2][TB][D_];   // 8 KB

    #pragma unroll
    for (int t = 0; t < TB; ++t)
        w_s[t][tid] = wqs[(size_t)(b * T_ + t0 + t) * D_ + tid];
    v_s[tid] = v[tid];
    __syncthreads();

    float acc0 = 0.f, acc1 = 0.f;
    const int do0 = h * 32;
    const uint4* u4 = (const uint4*)(uhb + ((size_t)(b * 64 + do0) * 256 + s) * 8);

    #pragma unroll 4
    for (int dd = 0; dd < 32; ++dd) {
        uint4 uu = u4[(size_t)dd * 256];   // 16B, coalesced across s-lanes
        float uf[8];
        uf[0] = asf(uu.x << 16); uf[1] = asf(uu.x & 0xffff0000u);
        uf[2] = asf(uu.y << 16); uf[3] = asf(uu.y & 0xffff0000u);
        uf[4] = asf(uu.z << 16); uf[5] = asf(uu.z & 0xffff0000u);
        uf[6] = asf(uu.w << 16); uf[7] = asf(uu.w & 0xffff0000u);

        const int dbase = (do0 + dd) * 8;
        #pragma unroll
        for (int j = 0; j < 8; ++j) {
            float vv = v_s[dbase + j];
            float x0 = w_s[0][dbase + j] + uf[j];
            float x1 = w_s[1][dbase + j] + uf[j];
            float r0 = __builtin_amdgcn_rcpf(__builtin_amdgcn_exp2f(x0) + 1.0f);
            float r1 = __builtin_amdgcn_rcpf(__builtin_amdgcn_exp2f(x1) + 1.0f);
            acc0 = fmaf(vv, r0, acc0);
            acc1 = fmaf(vv, r1, acc1);
        }
    }
    part[h][s] = make_float2(acc0, acc1);
    __syncthreads();

    // A per (t, s); score = Vsum - 2A, softmax shift-inv -> need Amin only
    float A0 = 0.f, A1 = 0.f;
    if (tid < 256) {
        float2 pa = part[0][tid], pb = part[1][tid];
        A0 = pa.x + pb.x;
        A1 = pa.y + pb.y;
        red[tid] = make_float2(A0, A1);
    }
    __syncthreads();
    for (int off = 128; off > 0; off >>= 1) {
        if (tid < off) {
            red[tid].x = fminf(red[tid].x, red[tid + off].x);
            red[tid].y = fminf(red[tid].y, red[tid + off].y);
        }
        __syncthreads();
    }
    float2 Amn = red[0];
    __syncthreads();

    float p0 = 0.f, p1 = 0.f;
    if (tid < 256) {
        float keep = 1.0f - (float)mask[b * S_ + tid];
        p0 = __builtin_amdgcn_exp2f(C2F * (Amn.x - A0)) * keep;
        p1 = __builtin_amdgcn_exp2f(C2F * (Amn.y - A1)) * keep;
        red[tid] = make_float2(p0, p1);
    }
    __syncthreads();
    for (int off = 128; off > 0; off >>= 1) {
        if (tid < off) {
            red[tid].x += red[tid + off].x;
            red[tid].y += red[tid + off].y;
        }
        __syncthreads();
    }
    float2 denom = red[0];

    if (tid < 256) {
        float a0 = p0 * __builtin_amdgcn_rcpf(denom.x);
        float a1 = p1 * __builtin_amdgcn_rcpf(denom.y);
        attn_out[(size_t)(b * T_ + t0 + 0) * S_ + tid] = a0;
        attn_out[(size_t)(b * T_ + t0 + 1) * S_ + tid] = a1;
        a_s[0][tid] = a0;
        a_s[1][tid] = a1;
    }
    __syncthreads();

    // fused out-projection: thread (d2=tid&255 -> d={2d2,2d2+1}), s-half h
    const int d2 = tid & 255;
    const int sh = h * 128;
    const unsigned short* cw = CWb + ((size_t)(b * S_) + sh) * D_ + 2 * d2;
    float m[TB][2] = {};
    #pragma unroll 8
    for (int s2 = 0; s2 < 128; ++s2) {
        unsigned int cc = *(const unsigned int*)(cw + (size_t)s2 * D_);
        float c0 = asf(cc << 16), c1 = asf(cc & 0xffff0000u);
        #pragma unroll
        for (int t = 0; t < TB; ++t) {
            float a = a_s[t][sh + s2];
            m[t][0] = fmaf(a, c0, m[t][0]);
            m[t][1] = fmaf(a, c1, m[t][1]);
        }
    }
    #pragma unroll
    for (int t = 0; t < TB; ++t) {
        mixp[h][t][2 * d2]     = m[t][0];
        mixp[h][t][2 * d2 + 1] = m[t][1];
    }
    __syncthreads();
    #pragma unroll
    for (int t = 0; t < TB; ++t) {
        size_t idx = (size_t)(b * T_ + t0 + t) * D_ + tid;
        out[idx] = mixp[0][t][tid] + mixp[1][t][tid] + OB[idx];
    }
}

extern "C" void kernel_launch(void* const* d_in, const int* in_sizes, int n_in,
                              void* d_out, int out_size, void* d_ws, size_t ws_size,
                              hipStream_t stream) {
    const float* output  = (const float*)d_in[0];
    const float* context = (const float*)d_in[1];
    const int*   mask    = (const int*)d_in[2];
    const float* Wq      = (const float*)d_in[3];
    const float* bq      = (const float*)d_in[4];
    const float* Wc      = (const float*)d_in[5];
    const float* v       = (const float*)d_in[6];
    const float* Wout    = (const float*)d_in[7];
    const float* bout    = (const float*)d_in[8];

    float* out  = (float*)d_out;                       // (B,T,D)
    float* attn = out + (size_t)B_ * T_ * D_;          // (B,T,S)

    char* ws = (char*)d_ws;
    float* wqs          = (float*)ws;                             // 2 MB fp32
    float* OB           = (float*)(ws + (2u << 20));              // 2 MB fp32
    unsigned short* uhb    = (unsigned short*)(ws + (4u << 20));  // 1 MB
    unsigned short* out_b  = (unsigned short*)(ws + (5u << 20));  // 1 MB
    unsigned short* ctx_b  = (unsigned short*)(ws + (6u << 20));  // 1 MB
    unsigned short* WqT    = (unsigned short*)(ws + (7u << 20));  // 0.5 MB
    unsigned short* WcT    = (unsigned short*)(ws + (7u << 20) + (512u << 10));
    unsigned short* WoutT  = (unsigned short*)(ws + (8u << 20));  // 1 MB
    unsigned short* CWb    = (unsigned short*)(ws + (9u << 20));  // 1 MB

    dim3 blk(256);

    prep<<<dim3(16, 32, 4), blk, 0, stream>>>(
        output, context, Wq, Wc, Wout, out_b, ctx_b, WqT, WcT, WoutT);

    // Pre-GEMMs, one dispatch (z-slices), all independent, K=512 each:
    //   z0: wqs = C2*(output@Wq + bq)            [mode 1]
    //   z1: uhb = bf16 C2*(context@Wc) permuted  [mode 3]
    //   z2: OB  = output@Wout_bot + bout         [mode 4]
    //   z3: CWb = bf16 context@Wout_top          [mode 5]
    GArgs gwq = { out_b, WqT,   bq,      wqs, 512, 512,   0, 1 };
    GArgs guh = { ctx_b, WcT,   nullptr, uhb, 512, 512,   0, 3 };
    GArgs gob = { out_b, WoutT, bout,    OB,  512, 1024, 512, 4 };
    GArgs gcw = { ctx_b, WoutT, nullptr, CWb, 512, 1024,   0, 5 };
    gemm2<512><<<dim3(16, 16, 4), blk, 0, stream>>>(gwq, guh, gob, gcw);

    // fused score + softmax + out-projection
    attn_fused<<<dim3(B_ * T_ / TB), dim3(512), 0, stream>>>(
        wqs, uhb, CWb, OB, mask, v, attn, out);
}

// Round 8
// 122.017 us; speedup vs baseline: 1.1257x; 1.1257x over previous
//
#include <hip/hip_runtime.h>
#include <hip/hip_bf16.h>

#define B_ 4
#define T_ 256
#define S_ 256
#define D_ 512
#define TB 2   // t's per attention block

typedef __bf16 bf16x8 __attribute__((ext_vector_type(8)));
typedef float  floatx4 __attribute__((ext_vector_type(4)));

#define C2F 2.885390081777926f  // 2*log2(e)

static __device__ __forceinline__ unsigned short f2bf(float x) {
    __hip_bfloat16 h = __float2bfloat16(x);
    return *reinterpret_cast<unsigned short*>(&h);
}
static __device__ __forceinline__ float asf(unsigned int u) {
    float f; __builtin_memcpy(&f, &u, 4); return f;
}

// ---------------------------------------------------------------------------
// Fragment-order layout (K=512 => 16 k-blocks of 32):
//   tile(mblk,kblk) = mblk*16 + kblk;  lane = (m&15) | (((k>>3)&3)<<4)
//   addr = (tile*64 + lane)*8 + (k&7)
// A wave's MFMA fragment = frag_base + tile*512 + lane*8 : one CONTIGUOUS
// 1 KB load per wave (no gathers, no KB-strided L2 channel hotspot).
// ---------------------------------------------------------------------------

// prep: z=0..3 -> Wq, Wc, Wout_top, Wout_bot transposed+converted into
//        fragment-order bf16 (LDS 32x32 transpose tiles).
//       z=4,5 -> output, context converted into fragment-order bf16.
__global__ __launch_bounds__(256) void prep(
    const float* __restrict__ output, const float* __restrict__ context,
    const float* __restrict__ Wq, const float* __restrict__ Wc,
    const float* __restrict__ Wout,
    unsigned short* __restrict__ out_f, unsigned short* __restrict__ ctx_f,
    unsigned short* __restrict__ Wq_f, unsigned short* __restrict__ Wc_f,
    unsigned short* __restrict__ WoT_f, unsigned short* __restrict__ WoB_f)
{
    const int tid = threadIdx.x;
    const int z = blockIdx.z;

    if (z >= 4) {
        // activations: M=1024 rows, K=512 -> 1024 frag tiles, 4 per block
        const float* src = (z == 4) ? output : context;
        unsigned short* dst = (z == 4) ? out_f : ctx_f;
        const int bid  = blockIdx.y * 16 + blockIdx.x;   // 0..255
        const int tile = bid * 4 + (tid >> 6);           // 0..1023
        const int lane = tid & 63;
        const int mblk = tile >> 4, kblk = tile & 15;
        const float* s = src + (size_t)(mblk * 16 + (lane & 15)) * 512
                             + kblk * 32 + (lane >> 4) * 8;
        float4 a = *(const float4*)s;
        float4 b = *(const float4*)(s + 4);
        uint4 pk;
        pk.x = (unsigned)f2bf(a.x) | ((unsigned)f2bf(a.y) << 16);
        pk.y = (unsigned)f2bf(a.z) | ((unsigned)f2bf(a.w) << 16);
        pk.z = (unsigned)f2bf(b.x) | ((unsigned)f2bf(b.y) << 16);
        pk.w = (unsigned)f2bf(b.z) | ((unsigned)f2bf(b.w) << 16);
        *(uint4*)(dst + (size_t)tile * 512 + lane * 8) = pk;   // coalesced 16B
        return;
    }

    // weights: W is (k, n) row-major with n-stride 512; emit W^T frag-order
    const float* W; unsigned short* WF; int krow0;
    if      (z == 0) { W = Wq;   WF = Wq_f;  krow0 = 0;   }
    else if (z == 1) { W = Wc;   WF = Wc_f;  krow0 = 0;   }
    else if (z == 2) { W = Wout; WF = WoT_f; krow0 = 0;   }
    else             { W = Wout; WF = WoB_f; krow0 = 512; }

    const int n0 = blockIdx.x * 32;
    const int k0 = blockIdx.y * 32;

    __shared__ float tile[32][33];
    const int c = tid & 31, r = tid >> 5;
    #pragma unroll
    for (int i = 0; i < 4; ++i)
        tile[r + 8 * i][c] = W[(size_t)(krow0 + k0 + r + 8 * i) * 512 + n0 + c];
    __syncthreads();
    #pragma unroll
    for (int i = 0; i < 4; ++i) {
        const int n = n0 + r + 8 * i;       // W^T row
        const int k = k0 + c;               // W^T col
        const int tl = (n >> 4) * 16 + (k >> 5);
        const int ln = (n & 15) | (((k >> 3) & 3) << 4);
        WF[((size_t)tl * 64 + ln) * 8 + (k & 7)] = f2bf(tile[c][r + 8 * i]);
    }
}

// ---------------------------------------------------------------------------
// MFMA bf16 GEMM from fragment-order inputs. M=1024, N=512, K=512 for all
// four z-slices. Wave = 16m x 32n (1 A-load + 2 B-loads -> 2 MFMAs per
// k-block; every load is a contiguous 1 KB wave-load). Barrier-free.
// Epilogue modes:
//   1: fp32 C2F*(acc + aux[col])          (wqs)
//   3: bf16 C2F*acc -> [b][d>>3][s][d&7]  (uhb)
//   4: fp32 acc + aux[col]                (OB = output@Wout_bot + bout)
//   5: bf16 acc, natural [row][col]       (CWb = context@Wout_top)
// ---------------------------------------------------------------------------
struct GArgs {
    const unsigned short* Af;
    const unsigned short* Bf;
    const float* aux;
    void* C;
    int mode;
};

__global__ __launch_bounds__(256) void gemm2(GArgs g0, GArgs g1, GArgs g2, GArgs g3)
{
    const int z = blockIdx.z;
    GArgs g = (z == 0) ? g0 : (z == 1) ? g1 : (z == 2) ? g2 : g3;

    const int tid  = threadIdx.x;
    const int wave = tid >> 6, lane = tid & 63;
    const int l15  = lane & 15, quad = lane >> 4;
    const int mblk = blockIdx.y * 4 + wave;      // 0..63
    const int nb0  = blockIdx.x * 2;             // 0..30

    const unsigned short* Ap  = g.Af + ((size_t)mblk * 16 * 64 + lane) * 8;
    const unsigned short* Bp0 = g.Bf + ((size_t)nb0 * 16 * 64 + lane) * 8;
    const unsigned short* Bp1 = Bp0 + (size_t)16 * 64 * 8;

    floatx4 acc[2];
    acc[0] = (floatx4){0.f, 0.f, 0.f, 0.f};
    acc[1] = (floatx4){0.f, 0.f, 0.f, 0.f};

    #pragma unroll 4
    for (int k = 0; k < 16; ++k) {
        bf16x8 a  = *(const bf16x8*)(Ap  + k * 512);
        bf16x8 b0 = *(const bf16x8*)(Bp0 + k * 512);
        bf16x8 b1 = *(const bf16x8*)(Bp1 + k * 512);
        acc[0] = __builtin_amdgcn_mfma_f32_16x16x32_bf16(a, b0, acc[0], 0, 0, 0);
        acc[1] = __builtin_amdgcn_mfma_f32_16x16x32_bf16(a, b1, acc[1], 0, 0, 0);
    }

    #pragma unroll
    for (int ni = 0; ni < 2; ++ni) {
        const int col = (nb0 + ni) * 16 + l15;
        const int rbase = mblk * 16 + quad * 4;
        if (g.mode == 3) {
            unsigned short* Cb = (unsigned short*)g.C;
            #pragma unroll
            for (int r = 0; r < 4; ++r) {
                int row = rbase + r, bb = row >> 8, ss = row & 255;
                Cb[((size_t)(bb * 64 + (col >> 3)) * 256 + ss) * 8 + (col & 7)]
                    = f2bf(C2F * acc[ni][r]);
            }
        } else if (g.mode == 5) {
            unsigned short* Cb = (unsigned short*)g.C;
            #pragma unroll
            for (int r = 0; r < 4; ++r)
                Cb[(size_t)(rbase + r) * 512 + col] = f2bf(acc[ni][r]);
        } else {
            float* Cf = (float*)g.C;
            float bv = g.aux ? g.aux[col] : 0.0f;
            #pragma unroll
            for (int r = 0; r < 4; ++r) {
                float val = acc[ni][r] + bv;
                if (g.mode == 1) val *= C2F;
                Cf[(size_t)(rbase + r) * 512 + col] = val;
            }
        }
    }
}

// ---------------------------------------------------------------------------
// Fused score + masked softmax + out-projection. 1024 threads (16 waves);
// 512 blocks -> 2 blocks/CU = 32 waves/CU. Thread (s=tid&255, h=tid>>8)
// owns d-quarter [128h, 128h+128) in the score phase.
// Softmax: score = Vsum - 2A and softmax is shift-invariant, so
// p = exp2(-C2F*A) directly (|C2F*A| <= ~55 < 127: no overflow; no max
// reduction needed). Sum via 64-lane shfl butterfly + 4 partials.
// ---------------------------------------------------------------------------
__global__ __launch_bounds__(1024) void attn_fused(
    const float* __restrict__ wqs,            // (B,T,D) pre-scaled fp32
    const unsigned short* __restrict__ uhb,   // (B,D/8,S,8) pre-scaled bf16
    const unsigned short* __restrict__ CWb,   // (B,S,D) bf16
    const float* __restrict__ OB,             // (B,T,D) fp32
    const int*   __restrict__ mask,           // (B,S)
    const float* __restrict__ v,              // (D)
    float* __restrict__ attn_out,             // (B,T,S) fp32
    float* __restrict__ out)                  // (B,T,D) fp32
{
    const int bg  = blockIdx.x;
    const int b   = bg / (T_ / TB);
    const int t0  = (bg % (T_ / TB)) * TB;
    const int tid = threadIdx.x;
    const int s   = tid & 255;
    const int h   = tid >> 8;    // 0..3

    __shared__ float  w_s[TB][D_];       // 4 KB
    __shared__ float  v_s[D_];           // 2 KB
    __shared__ float2 part[4][256];      // 8 KB
    __shared__ float2 wred[4];
    __shared__ float  a_s[TB][256];      // 2 KB
    __shared__ float  mixp[4][TB][D_];   // 16 KB

    if (tid < 512) {
        w_s[0][tid] = wqs[(size_t)(b * T_ + t0 + 0) * D_ + tid];
        w_s[1][tid] = wqs[(size_t)(b * T_ + t0 + 1) * D_ + tid];
        v_s[tid]    = v[tid];
    }
    __syncthreads();

    float acc0 = 0.f, acc1 = 0.f;
    const int dd0 = h * 16;   // d-chunk (8 wide) base
    const uint4* u4 = (const uint4*)(uhb + ((size_t)(b * 64 + dd0) * 256 + s) * 8);

    #pragma unroll 4
    for (int dd = 0; dd < 16; ++dd) {
        uint4 uu = u4[(size_t)dd * 256];   // contiguous 16B across s-lanes
        float uf[8];
        uf[0] = asf(uu.x << 16); uf[1] = asf(uu.x & 0xffff0000u);
        uf[2] = asf(uu.y << 16); uf[3] = asf(uu.y & 0xffff0000u);
        uf[4] = asf(uu.z << 16); uf[5] = asf(uu.z & 0xffff0000u);
        uf[6] = asf(uu.w << 16); uf[7] = asf(uu.w & 0xffff0000u);

        const int dbase = (dd0 + dd) * 8;
        #pragma unroll
        for (int j = 0; j < 8; ++j) {
            float vv = v_s[dbase + j];                    // wave-uniform
            float x0 = w_s[0][dbase + j] + uf[j];
            float x1 = w_s[1][dbase + j] + uf[j];
            float r0 = __builtin_amdgcn_rcpf(__builtin_amdgcn_exp2f(x0) + 1.0f);
            float r1 = __builtin_amdgcn_rcpf(__builtin_amdgcn_exp2f(x1) + 1.0f);
            acc0 = fmaf(vv, r0, acc0);
            acc1 = fmaf(vv, r1, acc1);
        }
    }
    part[h][s] = make_float2(acc0, acc1);
    __syncthreads();

    float p0 = 0.f, p1 = 0.f;
    if (tid < 256) {
        float A0 = part[0][tid].x + part[1][tid].x + part[2][tid].x + part[3][tid].x;
        float A1 = part[0][tid].y + part[1][tid].y + part[2][tid].y + part[3][tid].y;
        float keep = 1.0f - (float)mask[b * S_ + tid];
        p0 = __builtin_amdgcn_exp2f(-C2F * A0) * keep;
        p1 = __builtin_amdgcn_exp2f(-C2F * A1) * keep;
        float s0 = p0, s1 = p1;
        #pragma unroll
        for (int off = 1; off < 64; off <<= 1) {
            s0 += __shfl_xor(s0, off);
            s1 += __shfl_xor(s1, off);
        }
        if ((tid & 63) == 0) wred[tid >> 6] = make_float2(s0, s1);
    }
    __syncthreads();

    if (tid < 256) {
        float den0 = wred[0].x + wred[1].x + wred[2].x + wred[3].x;
        float den1 = wred[0].y + wred[1].y + wred[2].y + wred[3].y;
        float a0 = p0 * __builtin_amdgcn_rcpf(den0);
        float a1 = p1 * __builtin_amdgcn_rcpf(den1);
        attn_out[(size_t)(b * T_ + t0 + 0) * S_ + tid] = a0;
        attn_out[(size_t)(b * T_ + t0 + 1) * S_ + tid] = a1;
        a_s[0][tid] = a0;
        a_s[1][tid] = a1;
    }
    __syncthreads();

    // out-projection: thread (d2=tid&255 -> d={2d2,2d2+1}), s-quarter h
    const int d2 = tid & 255;
    const int sh = h * 64;
    const unsigned short* cw = CWb + ((size_t)(b * S_) + sh) * D_ + 2 * d2;
    float m[TB][2] = {};
    #pragma unroll 8
    for (int s2 = 0; s2 < 64; ++s2) {
        unsigned int cc = *(const unsigned int*)(cw + (size_t)s2 * D_);
        float c0 = asf(cc << 16), c1 = asf(cc & 0xffff0000u);
        #pragma unroll
        for (int t = 0; t < TB; ++t) {
            float a = a_s[t][sh + s2];
            m[t][0] = fmaf(a, c0, m[t][0]);
            m[t][1] = fmaf(a, c1, m[t][1]);
        }
    }
    #pragma unroll
    for (int t = 0; t < TB; ++t) {
        mixp[h][t][2 * d2]     = m[t][0];
        mixp[h][t][2 * d2 + 1] = m[t][1];
    }
    __syncthreads();

    {   // 1024 threads cover TB*512 outputs
        const int t = tid >> 9, d = tid & 511;
        size_t idx = (size_t)(b * T_ + t0 + t) * D_ + d;
        out[idx] = mixp[0][t][d] + mixp[1][t][d] + mixp[2][t][d] + mixp[3][t][d]
                 + OB[idx];
    }
}

extern "C" void kernel_launch(void* const* d_in, const int* in_sizes, int n_in,
                              void* d_out, int out_size, void* d_ws, size_t ws_size,
                              hipStream_t stream) {
    const float* output  = (const float*)d_in[0];
    const float* context = (const float*)d_in[1];
    const int*   mask    = (const int*)d_in[2];
    const float* Wq      = (const float*)d_in[3];
    const float* bq      = (const float*)d_in[4];
    const float* Wc      = (const float*)d_in[5];
    const float* v       = (const float*)d_in[6];
    const float* Wout    = (const float*)d_in[7];
    const float* bout    = (const float*)d_in[8];

    float* out  = (float*)d_out;                       // (B,T,D)
    float* attn = out + (size_t)B_ * T_ * D_;          // (B,T,S)

    char* ws = (char*)d_ws;
    float* wqs           = (float*)ws;                              // 2 MB
    float* OB            = (float*)(ws + (2u << 20));               // 2 MB
    unsigned short* uhb   = (unsigned short*)(ws + (4u << 20));     // 1 MB
    unsigned short* out_f = (unsigned short*)(ws + (5u << 20));     // 1 MB
    unsigned short* ctx_f = (unsigned short*)(ws + (6u << 20));     // 1 MB
    unsigned short* Wq_f  = (unsigned short*)(ws + (7u << 20));     // 0.5 MB
    unsigned short* Wc_f  = (unsigned short*)(ws + (7u << 20) + (512u << 10));
    unsigned short* WoT_f = (unsigned short*)(ws + (8u << 20));     // 0.5 MB
    unsigned short* WoB_f = (unsigned short*)(ws + (8u << 20) + (512u << 10));
    unsigned short* CWb   = (unsigned short*)(ws + (9u << 20));     // 1 MB

    dim3 blk(256);

    // fragment-order bf16 conversion of everything
    prep<<<dim3(16, 16, 6), blk, 0, stream>>>(
        output, context, Wq, Wc, Wout, out_f, ctx_f, Wq_f, Wc_f, WoT_f, WoB_f);

    // four independent GEMMs, one dispatch (z-slices), K=512 each:
    //   z0: wqs = C2*(output@Wq + bq)            [mode 1]
    //   z1: uhb = bf16 C2*(context@Wc) permuted  [mode 3]
    //   z2: OB  = output@Wout_bot + bout         [mode 4]
    //   z3: CWb = bf16 context@Wout_top          [mode 5]
    GArgs gwq = { out_f, Wq_f,  bq,      wqs, 1 };
    GArgs guh = { ctx_f, Wc_f,  nullptr, uhb, 3 };
    GArgs gob = { out_f, WoB_f, bout,    OB,  4 };
    GArgs gcw = { ctx_f, WoT_f, nullptr, CWb, 5 };
    gemm2<<<dim3(16, 16, 4), blk, 0, stream>>>(gwq, guh, gob, gcw);

    // fused score + softmax + out-projection
    attn_fused<<<dim3(B_ * T_ / TB), dim3(1024), 0, stream>>>(
        wqs, uhb, CWb, OB, mask, v, attn, out);
}